// Round 11
// baseline (34973.035 us; speedup 1.0000x reference)
//
#include <hip/hip_runtime.h>
#include <hip/hip_bf16.h>
#include <cstdint>
#include <cstddef>

// Problem dims
#define BB    128
#define SS    1024
#define INDIM 16
#define HH    256
#define EE    32
#define NEMB_ 64

// Decomposition: ONE block per batch group; 16 waves; wave w owns all 4 gates
// of hidden units [w*16, w*16+16). No inter-block communication at all.
#define NGRP 8
#define MB   16
#define NTHR 1024
#define NBLK 8

using frag_t = __attribute__((ext_vector_type(8))) short;  // 8 bf16 (4 VGPRs)
using f32x4  = __attribute__((ext_vector_type(4))) float;
typedef unsigned long long ull;

// LDS-only barrier (no vmcnt drain): lgkmcnt(0) seals our ds_writes, barrier
// rendezvous, sched_barrier stops hoisting (rule #18).
#define LBAR() do { asm volatile("s_waitcnt lgkmcnt(0)" ::: "memory"); \
  __builtin_amdgcn_s_barrier(); __builtin_amdgcn_sched_barrier(0); } while (0)

__device__ __forceinline__ short f2bf(float f) {
  union { float f; uint32_t u; } v; v.f = f;
  uint32_t r = (v.u + 0x7fffu + ((v.u >> 16) & 1u)) >> 16;  // RNE
  return (short)(uint16_t)r;
}
__device__ __forceinline__ float sigf(float x) { return 1.0f / (1.0f + __expf(-x)); }
__device__ __forceinline__ float tanh_fast(float x) { return 1.0f - 2.0f / (__expf(2.0f * x) + 1.0f); }

// Shared memory plan (84.6KB total; ldsW region reused by alphaTab after init):
//   [0,      65536): init = weight staging [256][128] bf16 ; runtime = alphaTab[64][256] f32
//   [65536,  82432): hT[2][16][264] bf16  (h tile, dbuf, rows padded +8 shorts)
//   [82432,  84608): redbufD[2][16][17] f32 (out partials, dbuf)
#define SM_BYTES 84608
#define HT_OFF   65536
#define RB_OFF   82432
#define HT_PAR   (16 * 264)
#define RB_PAR   (16 * 17)

__global__ __launch_bounds__(NTHR)
void ilstm_kernel(const int* __restrict__ e, const float* __restrict__ x,
                  const float* __restrict__ embt, const float* __restrict__ Wx1,
                  const float* __restrict__ Wx2, const float* __restrict__ Wh1,
                  const float* __restrict__ Wh2, const float* __restrict__ b1,
                  const float* __restrict__ b2, const float* __restrict__ We,
                  const float* __restrict__ be, const float* __restrict__ linW,
                  const float* __restrict__ linb, float* __restrict__ out)
{
  const int tid  = threadIdx.x;
  const int g    = blockIdx.x;     // batch group
  const int lane = tid & 63;
  const int wv   = tid >> 6;       // wave 0..15: units [wv*16, wv*16+16)
  const int lo4  = lane & 15;
  const int hi2  = lane >> 4;

  __shared__ __align__(16) unsigned char smem[SM_BYTES];
  unsigned short* ldsW     = (unsigned short*)smem;            // init only
  float*          alphaTab = (float*)smem;                     // after init
  unsigned short* hT       = (unsigned short*)(smem + HT_OFF);
  float*          redbufD  = (float*)(smem + RB_OFF);

  // ---------------- init: weights -> B-fragments in VGPRs ----------------
  // fB[set][gate][kstep]; kstep 8 = x-projection (K rows 16..31 zero).
  // Wave w's 16 cols of gate G live in panel p = G*2 + (w>=8), at (w&7)*16.
  frag_t fB[2][4][9];
  #pragma unroll
  for (int ws = 0; ws < 2; ++ws) {
    const float* W  = ws ? Wh2 : Wh1;
    const float* Wx = ws ? Wx2 : Wx1;
    for (int p = 0; p < 8; ++p) {
      __syncthreads();  // protect previous panel's gather
      for (int idx = tid; idx < 256 * 128; idx += NTHR) {
        int row = idx >> 7, c = idx & 127;
        ldsW[idx] = (unsigned short)f2bf(W[row * 1024 + p * 128 + c]);
      }
      __syncthreads();
      const int mine = (((wv >> 3) & 1) == (p & 1));
      const int G    = p >> 1;
      const int base = (wv & 7) * 16;
      if (mine) {
        #pragma unroll
        for (int kk = 0; kk < 8; ++kk) {
          frag_t f;
          #pragma unroll
          for (int j = 0; j < 8; ++j)
            f[j] = (short)ldsW[(kk * 32 + hi2 * 8 + j) * 128 + base + lo4];
          fB[ws][G][kk] = f;
        }
      }
      __syncthreads();
      for (int idx = tid; idx < INDIM * 128; idx += NTHR) {
        int row = idx >> 7, c = idx & 127;
        ldsW[idx] = (unsigned short)f2bf(Wx[row * 1024 + p * 128 + c]);
      }
      __syncthreads();
      if (mine) {
        frag_t f;
        #pragma unroll
        for (int j = 0; j < 8; ++j) {
          int k = hi2 * 8 + j;
          short v = 0;
          if (k < INDIM) v = (short)ldsW[k * 128 + base + lo4];
          f[j] = v;
        }
        fB[ws][G][8] = f;
      }
    }
  }
  __syncthreads();  // last gather done; ldsW region now becomes alphaTab

  // per-lane constants
  const int ug = wv * 16 + lo4;                 // global unit 0..255
  float bb1[4], bb2[4];
  #pragma unroll
  for (int G = 0; G < 4; ++G) { bb1[G] = b1[G * 256 + ug]; bb2[G] = b2[G * 256 + ug]; }
  const float lwv = linW[ug];
  const float lb  = linb[0];

  // alphaTab[id][j] = sigmoid(emb[id]@We[:,j] + be[j])  (fp32, 64KB)
  for (int idx = tid; idx < NEMB_ * HH; idx += NTHR) {
    int id = idx >> 8, j = idx & 255;
    float s = be[j];
    #pragma unroll
    for (int k = 0; k < EE; ++k) s += embt[id * EE + k] * We[k * HH + j];
    alphaTab[id * HH + j] = sigf(s);
  }
  // zero h tiles (h_{-1} = 0)
  for (int idx = tid; idx < 2 * HT_PAR; idx += NTHR) hT[idx] = 0;
  __syncthreads();

  // ---------------- main scan ----------------
  float cst[4] = {0.f, 0.f, 0.f, 0.f};         // c-state: unit ug, batches hi2*4+r

  // initial x fragment + e indices (t = 0); A-frag: row=batch lo4, k=hi2*8..
  frag_t ax;
  #pragma unroll
  for (int j = 0; j < 8; ++j) ax[j] = 0;
  if (hi2 < 2) {
    const float4* p = (const float4*)(x + ((size_t)(g * MB + lo4) * SS + 0) * INDIM + hi2 * 8);
    float4 v0 = p[0], v1 = p[1];
    ax[0] = f2bf(v0.x); ax[1] = f2bf(v0.y); ax[2] = f2bf(v0.z); ax[3] = f2bf(v0.w);
    ax[4] = f2bf(v1.x); ax[5] = f2bf(v1.y); ax[6] = f2bf(v1.z); ax[7] = f2bf(v1.w);
  }
  int e4v[4];
  #pragma unroll
  for (int r = 0; r < 4; ++r) e4v[r] = e[(size_t)(g * MB + hi2 * 4 + r) * SS + 0];

  for (int t = 0; t < SS; ++t) {
    const int par = t & 1;

    // (P0) the ONLY barrier: seals hT[par] (written at t-1) + redbufD[par^1]
    LBAR();

    // (P1) issue next-step x/e prefetch (converted at P7, shadow time)
    float4 xn0, xn1; int e4n[4];
    if (t + 1 < SS) {
      if (hi2 < 2) {
        const float4* p =
            (const float4*)(x + ((size_t)(g * MB + lo4) * SS + (t + 1)) * INDIM + hi2 * 8);
        xn0 = p[0]; xn1 = p[1];
      }
      #pragma unroll
      for (int r = 0; r < 4; ++r)
        e4n[r] = e[(size_t)(g * MB + hi2 * 4 + r) * SS + (t + 1)];
    }

    // (P2) MFMAs: x-projection + 8 h K-steps; acc[set][gate], col=unit, row=batch
    f32x4 acc[2][4];
    #pragma unroll
    for (int a = 0; a < 2; ++a)
      #pragma unroll
      for (int G = 0; G < 4; ++G) { f32x4 z = {0.f, 0.f, 0.f, 0.f}; acc[a][G] = z; }
    #pragma unroll
    for (int a = 0; a < 2; ++a)
      #pragma unroll
      for (int G = 0; G < 4; ++G)
        acc[a][G] = __builtin_amdgcn_mfma_f32_16x16x32_bf16(ax, fB[a][G][8], acc[a][G], 0, 0, 0);
    #pragma unroll
    for (int kk = 0; kk < 8; ++kk) {
      frag_t ah = *(const frag_t*)&hT[par * HT_PAR + lo4 * 264 + kk * 32 + hi2 * 8];
      #pragma unroll
      for (int a = 0; a < 2; ++a)
        #pragma unroll
        for (int G = 0; G < 4; ++G)
          acc[a][G] = __builtin_amdgcn_mfma_f32_16x16x32_bf16(ah, fB[a][G][kk], acc[a][G], 0, 0, 0);
    }

    // (P3) out-reduce for step t-1 (shadow; redbufD[par^1] sealed by P0 LBAR)
    if (t > 0 && tid < MB) {
      float s = lb;
      #pragma unroll
      for (int w = 0; w < 16; ++w) s += redbufD[(par ^ 1) * RB_PAR + w * 17 + tid];
      out[(size_t)(g * MB + tid) * SS + (t - 1)] = s;
    }

    // (P4) interp + bias + LSTM cell — fully lane-local (i,f,g,o same lane)
    float hv[4];
    #pragma unroll
    for (int r = 0; r < 4; ++r) {
      const float a  = alphaTab[e4v[r] * HH + ug];
      const float gi = a * (acc[0][0][r] + bb1[0]) + (1.f - a) * (acc[1][0][r] + bb2[0]);
      const float gf = a * (acc[0][1][r] + bb1[1]) + (1.f - a) * (acc[1][1][r] + bb2[1]);
      const float gg = a * (acc[0][2][r] + bb1[2]) + (1.f - a) * (acc[1][2][r] + bb2[2]);
      const float go = a * (acc[0][3][r] + bb1[3]) + (1.f - a) * (acc[1][3][r] + bb2[3]);
      cst[r] = sigf(gf) * cst[r] + sigf(gi) * tanh_fast(gg);
      hv[r]  = sigf(go) * tanh_fast(cst[r]);
    }

    // (P5) publish h_t into hT[par^1]: pair adjacent units, packed b32 writes
    #pragma unroll
    for (int r = 0; r < 4; ++r) {
      const float hn = __shfl_xor(hv[r], 1);    // neighbor unit's h
      if (!(lane & 1)) {
        const uint32_t pk = (uint32_t)(uint16_t)f2bf(hv[r]) |
                            ((uint32_t)(uint16_t)f2bf(hn) << 16);
        *(uint32_t*)&hT[(par ^ 1) * HT_PAR + (hi2 * 4 + r) * 264 + ug] = pk;
      }
    }

    // (P6) out partials: reduce h*lw over the wave's 16 units -> redbufD[par]
    {
      float p0 = hv[0] * lwv, p1 = hv[1] * lwv, p2 = hv[2] * lwv, p3 = hv[3] * lwv;
      #pragma unroll
      for (int m = 1; m <= 8; m <<= 1) {
        p0 += __shfl_xor(p0, m); p1 += __shfl_xor(p1, m);
        p2 += __shfl_xor(p2, m); p3 += __shfl_xor(p3, m);
      }
      if (lo4 == 0) {
        float* rb = &redbufD[par * RB_PAR + wv * 17 + hi2 * 4];
        rb[0] = p0; rb[1] = p1; rb[2] = p2; rb[3] = p3;
      }
    }

    // (P7) convert prefetched x/e (shadow time)
    if (t + 1 < SS) {
      frag_t f;
      #pragma unroll
      for (int j = 0; j < 8; ++j) f[j] = 0;
      if (hi2 < 2) {
        f[0] = f2bf(xn0.x); f[1] = f2bf(xn0.y); f[2] = f2bf(xn0.z); f[3] = f2bf(xn0.w);
        f[4] = f2bf(xn1.x); f[5] = f2bf(xn1.y); f[6] = f2bf(xn1.z); f[7] = f2bf(xn1.w);
      }
      ax = f;
      #pragma unroll
      for (int r = 0; r < 4; ++r) e4v[r] = e4n[r];
    }
  }

  // epilogue: last step's out
  __syncthreads();
  if (tid < MB) {
    const int parL = (SS - 1) & 1;
    float s = lb;
    #pragma unroll
    for (int w = 0; w < 16; ++w) s += redbufD[parL * RB_PAR + w * 17 + tid];
    out[(size_t)(g * MB + tid) * SS + (SS - 1)] = s;
  }
}

extern "C" void kernel_launch(void* const* d_in, const int* in_sizes, int n_in,
                              void* d_out, int out_size, void* d_ws, size_t ws_size,
                              hipStream_t stream) {
  const int*   e    = (const int*)d_in[0];
  const float* x    = (const float*)d_in[1];
  const float* embt = (const float*)d_in[2];
  const float* Wx1  = (const float*)d_in[3];
  const float* Wx2  = (const float*)d_in[4];
  const float* Wh1  = (const float*)d_in[5];
  const float* Wh2  = (const float*)d_in[6];
  const float* b1   = (const float*)d_in[7];
  const float* b2   = (const float*)d_in[8];
  const float* We   = (const float*)d_in[9];
  const float* be   = (const float*)d_in[10];
  const float* linW = (const float*)d_in[11];
  const float* linb = (const float*)d_in[12];
  float* out = (float*)d_out;

  // 8 independent blocks, one per batch group; no workspace, no coop launch,
  // no inter-block sync -> deterministic and hang-free by construction.
  ilstm_kernel<<<dim3(NBLK), dim3(NTHR), 0, stream>>>(
      e, x, embt, Wx1, Wx2, Wh1, Wh2, b1, b2, We, be, linW, linb, out);
}

// Round 12
// 2452.375 us; speedup vs baseline: 14.2609x; 14.2609x over previous
//
#include <hip/hip_runtime.h>
#include <hip/hip_bf16.h>
#include <cstdint>
#include <cstddef>

// Problem dims
#define BB    128
#define SS    1024
#define INDIM 16
#define HH    256
#define EE    32
#define NEMB_ 64

// Decomposition
#define NGRP 8    // batch groups
#define MB   16   // batches per group
#define NCHK 8    // hidden chunks (8 blocks per group)
#define HC   32   // hidden units per chunk (block computes 4*HC=128 gate cols)
#define NTHR 256  // 4 waves; wave w owns gate-type w
#define NBLK 64   // 8 groups x 8 chunks

using frag_t = __attribute__((ext_vector_type(8))) short;  // 8 bf16 (4 VGPRs)
using f32x4  = __attribute__((ext_vector_type(4))) float;
typedef unsigned long long ull;

// Identity RMW "load": executes AT the device coherence point (IF), unlike a
// plain sc1 load which the R7/R9 counters show round-tripping to HBM every
// poll (FETCH_SIZE tracked poll bytes). Theory: RMW operates on the
// CP-resident line the producer's swap installed -> poll period drops from
// HBM latency (~900cy) to CP latency.
#define ALRMW(p) __hip_atomic_fetch_add((ull*)(p), 0ull, __ATOMIC_RELAXED, __HIP_MEMORY_SCOPE_AGENT)

// LDS-only barrier: does NOT drain vmcnt (unlike __syncthreads), so global
// loads/stores stay in flight across it. lgkmcnt(0) orders the ds_writes.
#define LBAR() do { asm volatile("s_waitcnt lgkmcnt(0)" ::: "memory"); \
  __builtin_amdgcn_s_barrier(); __builtin_amdgcn_sched_barrier(0); } while (0)

__device__ __forceinline__ short f2bf(float f) {
  union { float f; uint32_t u; } v; v.f = f;
  uint32_t r = (v.u + 0x7fffu + ((v.u >> 16) & 1u)) >> 16;  // RNE
  return (short)(uint16_t)r;
}
__device__ __forceinline__ float sigf(float x) { return 1.0f / (1.0f + __expf(-x)); }
__device__ __forceinline__ float tanh_fast(float x) { return 1.0f - 2.0f / (__expf(2.0f * x) + 1.0f); }

// Exchange: hx[par][g][row=batch][slot=hidden_pair] : u64 = (tag<<32)|(2xbf16).
// Per (par,g) tile: 16 rows x 128 slots = 2048 u64 = 16KB. Total 256KB in d_ws.

__global__ __launch_bounds__(NTHR, 1)
void ilstm_kernel(const int* __restrict__ e, const float* __restrict__ x,
                  const float* __restrict__ embt, const float* __restrict__ Wx1,
                  const float* __restrict__ Wx2, const float* __restrict__ Wh1,
                  const float* __restrict__ Wh2, const float* __restrict__ b1,
                  const float* __restrict__ b2, const float* __restrict__ We,
                  const float* __restrict__ be, const float* __restrict__ linW,
                  const float* __restrict__ linb, float* __restrict__ out,
                  ull* __restrict__ hx, float* __restrict__ partial,
                  int use_partial)
{
  const int tid  = threadIdx.x;
  const int bid  = blockIdx.x;
  const int g    = bid & 7;        // batch group
  const int ch   = bid >> 3;       // hidden chunk
  const int j0   = ch * HC;
  const int lane = tid & 63;
  const int wv   = tid >> 6;       // wave id == gate type (i,f,g,o)
  const int lo4  = lane & 15;
  const int hi2  = lane >> 4;

  __shared__ unsigned short ldsW[HH * 128];      // 64KB weight staging (bf16 bits)
  __shared__ unsigned hstageU[MB][132];          // 8.4KB h tile (u32 = 2 bf16), padded
  __shared__ float alphaTab[NEMB_][HC];          // 8KB  sigmoid(emb@We+be) per emb idx
  __shared__ float gatesLds[4][MB][HC + 1];      // gate exchange, padded
  __shared__ float redbuf[MB][MB];               // [jpair][batch] out partials
  __shared__ float biasLds[2][128];
  __shared__ float linWs[HC];

  // ---------------- init: weights -> B-fragments in VGPRs ----------------
  frag_t fB[2][2][9];  // [W1/W2][ntile][kstep]; kstep 8 = x-projection (K rows 16..31 zero)
  #pragma unroll
  for (int ws = 0; ws < 2; ++ws) {
    const float* W = ws ? Wh2 : Wh1;
    for (int idx = tid; idx < HH * 128; idx += NTHR) {
      int row = idx >> 7, c = idx & 127;
      int span = c >> 5, cc = c & 31;
      ldsW[idx] = (unsigned short)f2bf(W[row * 1024 + span * 256 + j0 + cc]);
    }
    __syncthreads();
    #pragma unroll
    for (int n = 0; n < 2; ++n)
      #pragma unroll
      for (int kk = 0; kk < 8; ++kk) {
        frag_t f;
        #pragma unroll
        for (int j = 0; j < 8; ++j)
          f[j] = (short)ldsW[(kk * 32 + hi2 * 8 + j) * 128 + (wv * 32 + n * 16 + lo4)];
        fB[ws][n][kk] = f;
      }
    __syncthreads();
    const float* Wx = ws ? Wx2 : Wx1;
    for (int idx = tid; idx < INDIM * 128; idx += NTHR) {
      int row = idx >> 7, c = idx & 127;
      int span = c >> 5, cc = c & 31;
      ldsW[idx] = (unsigned short)f2bf(Wx[row * 1024 + span * 256 + j0 + cc]);
    }
    __syncthreads();
    #pragma unroll
    for (int n = 0; n < 2; ++n) {
      frag_t f;
      #pragma unroll
      for (int j = 0; j < 8; ++j) {
        int k = hi2 * 8 + j;
        short v = 0;
        if (k < INDIM) v = (short)ldsW[k * 128 + (wv * 32 + n * 16 + lo4)];
        f[j] = v;
      }
      fB[ws][n][8] = f;
    }
    __syncthreads();
  }

  if (tid < 128) {
    int span = tid >> 5, cc = tid & 31;
    biasLds[0][tid] = b1[span * 256 + j0 + cc];
    biasLds[1][tid] = b2[span * 256 + j0 + cc];
  }
  if (tid < HC) linWs[tid] = linW[j0 + tid];
  for (int idx = tid; idx < NEMB_ * HC; idx += NTHR) {
    int id = idx >> 5, j = idx & 31;
    float s = be[j0 + j];
    #pragma unroll
    for (int k = 0; k < EE; ++k) s += embt[id * EE + k] * We[k * HH + j0 + j];
    alphaTab[id][j] = sigf(s);
  }
  __syncthreads();

  // ---------------- main scan ----------------
  const int bcell = tid & 15, jp = tid >> 4;   // producer: batch=bcell, hidden 2jp,2jp+1
  const int srow  = tid >> 4, scol8 = tid & 15; // consumer: row srow, u64 slots scol8*8..+8
  const float lw0 = linWs[2 * jp], lw1 = linWs[2 * jp + 1];
  const float lb = linb[0];
  float c0 = 0.f, c1 = 0.f;

  // initial x fragment + e indices (t = 0)
  frag_t ax;
  #pragma unroll
  for (int j = 0; j < 8; ++j) ax[j] = 0;
  if (hi2 < 2) {
    const float4* p = (const float4*)(x + ((size_t)(g * MB + lo4) * SS + 0) * INDIM + hi2 * 8);
    float4 v0 = p[0], v1 = p[1];
    ax[0] = f2bf(v0.x); ax[1] = f2bf(v0.y); ax[2] = f2bf(v0.z); ax[3] = f2bf(v0.w);
    ax[4] = f2bf(v1.x); ax[5] = f2bf(v1.y); ax[6] = f2bf(v1.z); ax[7] = f2bf(v1.w);
  }
  int e4v[4];
  #pragma unroll
  for (int r = 0; r < 4; ++r) e4v[r] = e[(size_t)(g * MB + hi2 * 4 + r) * SS + 0];

  const size_t prodIdx = (size_t)bcell * 128 + (size_t)ch * 16 + jp;
  const size_t consIdx = (size_t)srow * 128 + (size_t)scol8 * 8;

  for (int t = 0; t < SS; ++t) {
    const int par = t & 1;

    // (P0) x-MFMAs first: independent of h, runs while producers' swaps land
    f32x4 acc[2][2];
    #pragma unroll
    for (int a = 0; a < 2; ++a)
      #pragma unroll
      for (int n = 0; n < 2; ++n) { f32x4 z = {0.f, 0.f, 0.f, 0.f}; acc[a][n] = z; }
    acc[0][0] = __builtin_amdgcn_mfma_f32_16x16x32_bf16(ax, fB[0][0][8], acc[0][0], 0, 0, 0);
    acc[0][1] = __builtin_amdgcn_mfma_f32_16x16x32_bf16(ax, fB[0][1][8], acc[0][1], 0, 0, 0);
    acc[1][0] = __builtin_amdgcn_mfma_f32_16x16x32_bf16(ax, fB[1][0][8], acc[1][0], 0, 0, 0);
    acc[1][1] = __builtin_amdgcn_mfma_f32_16x16x32_bf16(ax, fB[1][1][8], acc[1][1], 0, 0, 0);

    // (P1) poll tagged h data via identity-RMW (CP-resident read): tag==t
    //      means payload (same 8B) is step-t h.
    ull v0, v1, v2, v3, v4, v5, v6, v7;
    {
      ull* src = hx + (size_t)(par * NGRP + g) * 2048 + consIdx;
      const ull tg = (ull)(unsigned)t;
      for (;;) {
        v0 = ALRMW(&src[0]); v1 = ALRMW(&src[1]);
        v2 = ALRMW(&src[2]); v3 = ALRMW(&src[3]);
        v4 = ALRMW(&src[4]); v5 = ALRMW(&src[5]);
        v6 = ALRMW(&src[6]); v7 = ALRMW(&src[7]);
        bool ok = ((v0 >> 32) == tg) & ((v1 >> 32) == tg) &
                  ((v2 >> 32) == tg) & ((v3 >> 32) == tg) &
                  ((v4 >> 32) == tg) & ((v5 >> 32) == tg) &
                  ((v6 >> 32) == tg) & ((v7 >> 32) == tg);
        if (ok) break;
      }
    }

    // (P2) strip tags -> LDS h tile (32B/thread, two b128 writes)
    {
      uint4 w0 = { (unsigned)v0, (unsigned)v1, (unsigned)v2, (unsigned)v3 };
      uint4 w1 = { (unsigned)v4, (unsigned)v5, (unsigned)v6, (unsigned)v7 };
      *(uint4*)&hstageU[srow][scol8 * 8]     = w0;
      *(uint4*)&hstageU[srow][scol8 * 8 + 4] = w1;
    }
    LBAR();

    // (P3) issue next-step x/e prefetch; stays in flight across the LDS-only
    //      barriers, consumed at (P7)
    float4 xn0, xn1; int e4n[4];
    if (t + 1 < SS) {
      if (hi2 < 2) {
        const float4* p =
            (const float4*)(x + ((size_t)(g * MB + lo4) * SS + (t + 1)) * INDIM + hi2 * 8);
        xn0 = p[0]; xn1 = p[1];
      }
      #pragma unroll
      for (int r = 0; r < 4; ++r)
        e4n[r] = e[(size_t)(g * MB + hi2 * 4 + r) * SS + (t + 1)];
    }

    // (P4) h-MFMAs from LDS fragments
    #pragma unroll
    for (int kk = 0; kk < 8; ++kk) {
      frag_t ah = *(const frag_t*)&hstageU[lo4][kk * 16 + hi2 * 4];
      acc[0][0] = __builtin_amdgcn_mfma_f32_16x16x32_bf16(ah, fB[0][0][kk], acc[0][0], 0, 0, 0);
      acc[0][1] = __builtin_amdgcn_mfma_f32_16x16x32_bf16(ah, fB[0][1][kk], acc[0][1], 0, 0, 0);
      acc[1][0] = __builtin_amdgcn_mfma_f32_16x16x32_bf16(ah, fB[1][0][kk], acc[1][0], 0, 0, 0);
      acc[1][1] = __builtin_amdgcn_mfma_f32_16x16x32_bf16(ah, fB[1][1][kk], acc[1][1], 0, 0, 0);
    }

    // (P5) alpha-interpolate + bias -> gatesLds (C layout: col=lane&15, row=hi2*4+r)
    #pragma unroll
    for (int n = 0; n < 2; ++n) {
      const float bb1 = biasLds[0][wv * 32 + n * 16 + lo4];
      const float bb2 = biasLds[1][wv * 32 + n * 16 + lo4];
      #pragma unroll
      for (int r = 0; r < 4; ++r) {
        const float a = alphaTab[e4v[r]][n * 16 + lo4];
        const float p1 = acc[0][n][r] + bb1;
        const float p2 = acc[1][n][r] + bb2;
        gatesLds[wv][hi2 * 4 + r][n * 16 + lo4] = a * p1 + (1.f - a) * p2;
      }
    }
    LBAR();

    // (P6) cell update; publish via non-returning atomic swap at device scope
    {
      const float gi0 = gatesLds[0][bcell][2 * jp];
      const float gf0 = gatesLds[1][bcell][2 * jp];
      const float gg0 = gatesLds[2][bcell][2 * jp];
      const float go0 = gatesLds[3][bcell][2 * jp];
      const float gi1 = gatesLds[0][bcell][2 * jp + 1];
      const float gf1 = gatesLds[1][bcell][2 * jp + 1];
      const float gg1 = gatesLds[2][bcell][2 * jp + 1];
      const float go1 = gatesLds[3][bcell][2 * jp + 1];
      c0 = sigf(gf0) * c0 + sigf(gi0) * tanh_fast(gg0);
      c1 = sigf(gf1) * c1 + sigf(gi1) * tanh_fast(gg1);
      const float h0 = sigf(go0) * tanh_fast(c0);
      const float h1 = sigf(go1) * tanh_fast(c1);
      if (t + 1 < SS) {
        const uint32_t pk = (uint32_t)(uint16_t)f2bf(h0) | ((uint32_t)(uint16_t)f2bf(h1) << 16);
        const ull pv = ((ull)(unsigned)(t + 1) << 32) | (ull)pk;
        ull* dst = &hx[(size_t)(((par ^ 1) * NGRP) + g) * 2048 + prodIdx];
        asm volatile("global_atomic_swap_x2 %0, %1, off sc1"
                     :: "v"(dst), "v"(pv) : "memory");
      }
      redbuf[jp][bcell] = h0 * lw0 + h1 * lw1;
    }
    LBAR();

    // (P7) convert prefetched x/e (overlaps peers' detect window), out-reduce
    if (t + 1 < SS) {
      frag_t f;
      #pragma unroll
      for (int j = 0; j < 8; ++j) f[j] = 0;
      if (hi2 < 2) {
        f[0] = f2bf(xn0.x); f[1] = f2bf(xn0.y); f[2] = f2bf(xn0.z); f[3] = f2bf(xn0.w);
        f[4] = f2bf(xn1.x); f[5] = f2bf(xn1.y); f[6] = f2bf(xn1.z); f[7] = f2bf(xn1.w);
      }
      ax = f;
      #pragma unroll
      for (int r = 0; r < 4; ++r) e4v[r] = e4n[r];
    }
    if (tid >= 16 && tid < 32) {
      const int b = tid - 16;
      float s = 0.f;
      #pragma unroll
      for (int q = 0; q < MB; ++q) s += redbuf[q][b];
      if (use_partial) {
        // plain store, no contention; kernel2 sums chunks and adds bias
        partial[((size_t)(g * NCHK + ch) * MB + b) * SS + t] = s;
      } else {
        atomicAdd(&out[(size_t)(g * MB + b) * SS + t], s + ((ch == 0) ? lb : 0.f));
      }
    }
  }
}

__global__ __launch_bounds__(256)
void sum_out_kernel(const float* __restrict__ partial, const float* __restrict__ linb,
                    float* __restrict__ out) {
  const int i = blockIdx.x * 256 + threadIdx.x;      // over BB*SS
  if (i >= BB * SS) return;
  const int b = i >> 10, t = i & 1023;
  const int g = b >> 4, bb = b & 15;
  const float* p = partial + ((size_t)g * NCHK * MB + bb) * SS + t;
  float s = linb[0];
  #pragma unroll
  for (int c = 0; c < NCHK; ++c) s += p[(size_t)c * MB * SS];
  out[i] = s;
}

extern "C" void kernel_launch(void* const* d_in, const int* in_sizes, int n_in,
                              void* d_out, int out_size, void* d_ws, size_t ws_size,
                              hipStream_t stream) {
  const int*   e    = (const int*)d_in[0];
  const float* x    = (const float*)d_in[1];
  const float* embt = (const float*)d_in[2];
  const float* Wx1  = (const float*)d_in[3];
  const float* Wx2  = (const float*)d_in[4];
  const float* Wh1  = (const float*)d_in[5];
  const float* Wh2  = (const float*)d_in[6];
  const float* b1   = (const float*)d_in[7];
  const float* b2   = (const float*)d_in[8];
  const float* We   = (const float*)d_in[9];
  const float* be   = (const float*)d_in[10];
  const float* linW = (const float*)d_in[11];
  const float* linb = (const float*)d_in[12];
  float* out = (float*)d_out;

  ull* hx = (ull*)d_ws;
  const size_t hx_bytes = (size_t)2 * NGRP * MB * 128 * sizeof(ull);  // 256KB
  const size_t part_bytes = (size_t)NBLK * MB * SS * sizeof(float);   // 4MB
  float* partial = (float*)((char*)d_ws + hx_bytes);
  const int use_partial = (ws_size >= hx_bytes + part_bytes) ? 1 : 0;

  hipMemsetAsync(d_out, 0, (size_t)BB * SS * sizeof(float), stream);
  hipMemsetAsync(d_ws, 0, hx_bytes, stream);   // tags=0 == step-0 target; data=h0=0

  void* args[] = { (void*)&e, (void*)&x, (void*)&embt, (void*)&Wx1, (void*)&Wx2,
                   (void*)&Wh1, (void*)&Wh2, (void*)&b1, (void*)&b2, (void*)&We,
                   (void*)&be, (void*)&linW, (void*)&linb, (void*)&out, (void*)&hx,
                   (void*)&partial, (void*)&use_partial };
  hipError_t err = hipLaunchCooperativeKernel(reinterpret_cast<void*>(ilstm_kernel),
                                              dim3(NBLK), dim3(NTHR),
                                              args, 0, stream);
  if (err != hipSuccess) {
    // fallback: plain launch; 64 blocks <= 256 CUs -> co-resident
    ilstm_kernel<<<dim3(NBLK), dim3(NTHR), 0, stream>>>(
        e, x, embt, Wx1, Wx2, Wh1, Wh2, b1, b2, We, be, linW, linb, out, hx,
        partial, use_partial);
  }
  if (use_partial) {
    sum_out_kernel<<<dim3((BB * SS + 255) / 256), dim3(256), 0, stream>>>(
        partial, linb, out);
  }
}